// Round 1
// baseline (1370.187 us; speedup 1.0000x reference)
//
#include <hip/hip_runtime.h>
#include <cfloat>
#include <cmath>

#define NEG_SLOPE 0.2f
#define SOFT_EPS 1e-16f

__device__ __forceinline__ float leaky(float x) { return x > 0.f ? x : NEG_SLOPE * x; }

// order-monotonic encoding of float into unsigned (for hardware atomicMax)
__device__ __forceinline__ unsigned enc_f(float f) {
  unsigned u = __float_as_uint(f);
  return (u & 0x80000000u) ? ~u : (u | 0x80000000u);
}
__device__ __forceinline__ float dec_f(unsigned e) {
  unsigned u = (e & 0x80000000u) ? (e ^ 0x80000000u) : ~e;
  return __uint_as_float(u);
}

// ---------------- CSR build ----------------
__global__ void count_deg(const int* __restrict__ ei, int E, int N, int* __restrict__ counts) {
  int e = blockIdx.x * blockDim.x + threadIdx.x;
  int Etot = E + N;
  if (e >= Etot) return;
  int d = (e < E) ? ei[E + e] : (e - E);
  atomicAdd(&counts[d], 1);
}

__global__ __launch_bounds__(256) void chunk_sum(const int* __restrict__ counts,
                                                 int* __restrict__ chunkSum, int N) {
  __shared__ int sc[256];
  int b = blockIdx.x, t = threadIdx.x;
  int base = b * 2048 + t * 8;
  int s = 0;
#pragma unroll
  for (int i = 0; i < 8; ++i) { int idx = base + i; if (idx < N) s += counts[idx]; }
  sc[t] = s; __syncthreads();
  for (int o = 128; o > 0; o >>= 1) { if (t < o) sc[t] += sc[t + o]; __syncthreads(); }
  if (t == 0) chunkSum[b] = sc[0];
}

__global__ void scan_chunks(const int* __restrict__ chunkSum, int* __restrict__ chunkOff,
                            int nb, int* __restrict__ row_start, int N, int Etot) {
  if (threadIdx.x == 0 && blockIdx.x == 0) {
    int r = 0;
    for (int b = 0; b < nb; ++b) { chunkOff[b] = r; r += chunkSum[b]; }
    row_start[N] = Etot;
  }
}

__global__ __launch_bounds__(256) void scan_emit(const int* __restrict__ counts,
    const int* __restrict__ chunkOff, int* __restrict__ row_start,
    int* __restrict__ write_ptr, int N) {
  __shared__ int sc[256];
  int b = blockIdx.x, t = threadIdx.x;
  int base = b * 2048 + t * 8;
  int v[8]; int s = 0;
#pragma unroll
  for (int i = 0; i < 8; ++i) { int idx = base + i; v[i] = (idx < N) ? counts[idx] : 0; s += v[i]; }
  sc[t] = s; __syncthreads();
  for (int o = 1; o < 256; o <<= 1) {
    int x = (t >= o) ? sc[t - o] : 0;
    __syncthreads();
    sc[t] += x;
    __syncthreads();
  }
  int run = chunkOff[b] + sc[t] - s;   // exclusive prefix for this thread
#pragma unroll
  for (int i = 0; i < 8; ++i) {
    int idx = base + i;
    if (idx < N) { row_start[idx] = run; write_ptr[idx] = run; }
    run += v[i];
  }
}

__global__ void scatter_edges(const int* __restrict__ ei, int E, int N,
                              int* __restrict__ write_ptr, int* __restrict__ edge_src) {
  int e = blockIdx.x * blockDim.x + threadIdx.x;
  int Etot = E + N;
  if (e >= Etot) return;
  int s, d;
  if (e < E) { s = ei[e]; d = ei[E + e]; } else { s = e - E; d = e - E; }
  int pos = atomicAdd(&write_ptr[d], 1);
  edge_src[pos] = s;
}

// ---------------- GEMM: C[N,256] = A[N,K] * B[K,256] ----------------
__global__ __launch_bounds__(256) void gemm_f32(const float* __restrict__ A,
    const float* __restrict__ B, float* __restrict__ C, int N, int K) {
  __shared__ float As[16][65];
  __shared__ float Bs[16][65];
  int t = threadIdx.x;
  int tx = t & 15, ty = t >> 4;
  int row0 = blockIdx.y * 64, col0 = blockIdx.x * 64;
  float acc[4][4] = {};
  for (int k0 = 0; k0 < K; k0 += 16) {
    {
      int m = t >> 2;
      int kk = (t & 3) << 2;
      int r = row0 + m;
      float4 av = make_float4(0.f, 0.f, 0.f, 0.f);
      if (r < N) av = *(const float4*)(A + (long)r * K + k0 + kk);
      As[kk + 0][m] = av.x; As[kk + 1][m] = av.y; As[kk + 2][m] = av.z; As[kk + 3][m] = av.w;
    }
    {
      int bk = t >> 4;
      int nn = (t & 15) << 2;
      float4 bv = *(const float4*)(B + (long)(k0 + bk) * 256 + col0 + nn);
      Bs[bk][nn + 0] = bv.x; Bs[bk][nn + 1] = bv.y; Bs[bk][nn + 2] = bv.z; Bs[bk][nn + 3] = bv.w;
    }
    __syncthreads();
#pragma unroll
    for (int kk = 0; kk < 16; ++kk) {
      float a[4], b[4];
#pragma unroll
      for (int i = 0; i < 4; ++i) a[i] = As[kk][(ty << 2) + i];
#pragma unroll
      for (int j = 0; j < 4; ++j) b[j] = Bs[kk][(tx << 2) + j];
#pragma unroll
      for (int i = 0; i < 4; ++i)
#pragma unroll
        for (int j = 0; j < 4; ++j) acc[i][j] += a[i] * b[j];
    }
    __syncthreads();
  }
#pragma unroll
  for (int i = 0; i < 4; ++i) {
    int r = row0 + (ty << 2) + i;
    if (r < N) {
      float4 v = make_float4(acc[i][0], acc[i][1], acc[i][2], acc[i][3]);
      *(float4*)(C + (long)r * 256 + col0 + (tx << 2)) = v;
    }
  }
}

// ---------------- attention dot: a_src[n,h], a_dst[n,h] ----------------
__global__ __launch_bounds__(256) void attn_dot(const float* __restrict__ g,
    const float* __restrict__ atts, const float* __restrict__ attd,
    float* __restrict__ a_src, float* __restrict__ a_dst, int N) {
  int lane = threadIdx.x & 63;
  int n = blockIdx.x * 4 + (threadIdx.x >> 6);
  if (n >= N) return;
  float4 gv = *(const float4*)(g + (long)n * 256 + lane * 4);
  float4 s4 = *(const float4*)(atts + lane * 4);
  float4 d4 = *(const float4*)(attd + lane * 4);
  float ds = gv.x * s4.x + gv.y * s4.y + gv.z * s4.z + gv.w * s4.w;
  float dd = gv.x * d4.x + gv.y * d4.y + gv.z * d4.z + gv.w * d4.w;
  for (int m = 1; m < 16; m <<= 1) {
    ds += __shfl_xor(ds, m, 64);
    dd += __shfl_xor(dd, m, 64);
  }
  if ((lane & 15) == 0) {
    a_src[n * 4 + (lane >> 4)] = ds;
    a_dst[n * 4 + (lane >> 4)] = dd;
  }
}

// ---------------- per-dst softmax + aggregate + bias + tanh ----------------
__global__ __launch_bounds__(256) void attn_agg(const float* __restrict__ g,
    const float* __restrict__ a_src, const float* __restrict__ a_dst,
    const int* __restrict__ row_start, const int* __restrict__ edge_src,
    const float* __restrict__ bias, float* __restrict__ hout, int N) {
  int lane = threadIdx.x & 63;
  int n = blockIdx.x * 4 + (threadIdx.x >> 6);
  if (n >= N) return;
  int beg = row_start[n], end = row_start[n + 1];
  int hof = lane >> 4;  // head owning channels [4*lane, 4*lane+4)
  float ad0 = a_dst[n * 4 + 0], ad1 = a_dst[n * 4 + 1];
  float ad2 = a_dst[n * 4 + 2], ad3 = a_dst[n * 4 + 3];
  // pass 1: per-head max
  float m0 = -FLT_MAX, m1 = -FLT_MAX, m2 = -FLT_MAX, m3 = -FLT_MAX;
  for (int i = beg + lane; i < end; i += 64) {
    const float* as = a_src + (long)edge_src[i] * 4;
    m0 = fmaxf(m0, leaky(as[0] + ad0));
    m1 = fmaxf(m1, leaky(as[1] + ad1));
    m2 = fmaxf(m2, leaky(as[2] + ad2));
    m3 = fmaxf(m3, leaky(as[3] + ad3));
  }
  for (int mm = 1; mm < 64; mm <<= 1) {
    m0 = fmaxf(m0, __shfl_xor(m0, mm, 64));
    m1 = fmaxf(m1, __shfl_xor(m1, mm, 64));
    m2 = fmaxf(m2, __shfl_xor(m2, mm, 64));
    m3 = fmaxf(m3, __shfl_xor(m3, mm, 64));
  }
  // pass 2: denom
  float d0 = 0.f, d1 = 0.f, d2 = 0.f, d3 = 0.f;
  for (int i = beg + lane; i < end; i += 64) {
    const float* as = a_src + (long)edge_src[i] * 4;
    d0 += expf(leaky(as[0] + ad0) - m0);
    d1 += expf(leaky(as[1] + ad1) - m1);
    d2 += expf(leaky(as[2] + ad2) - m2);
    d3 += expf(leaky(as[3] + ad3) - m3);
  }
  for (int mm = 1; mm < 64; mm <<= 1) {
    d0 += __shfl_xor(d0, mm, 64);
    d1 += __shfl_xor(d1, mm, 64);
    d2 += __shfl_xor(d2, mm, 64);
    d3 += __shfl_xor(d3, mm, 64);
  }
  float adh = (hof == 0) ? ad0 : (hof == 1) ? ad1 : (hof == 2) ? ad2 : ad3;
  float mh  = (hof == 0) ? m0  : (hof == 1) ? m1  : (hof == 2) ? m2  : m3;
  float dh  = ((hof == 0) ? d0 : (hof == 1) ? d1 : (hof == 2) ? d2 : d3) + SOFT_EPS;
  // pass 3: weighted gather
  float4 acc = make_float4(0.f, 0.f, 0.f, 0.f);
  for (int i = beg; i < end; ++i) {
    int s = edge_src[i];
    float e = leaky(a_src[(long)s * 4 + hof] + adh);
    float alpha = expf(e - mh) / dh;
    float4 gv = *(const float4*)(g + (long)s * 256 + lane * 4);
    acc.x += alpha * gv.x; acc.y += alpha * gv.y;
    acc.z += alpha * gv.z; acc.w += alpha * gv.w;
  }
  float4 bv = *(const float4*)(bias + lane * 4);
  float4 o;
  o.x = tanhf(acc.x + bv.x); o.y = tanhf(acc.y + bv.y);
  o.z = tanhf(acc.z + bv.z); o.w = tanhf(acc.w + bv.w);
  *(float4*)(hout + (long)n * 256 + lane * 4) = o;
}

// ---------------- readout ----------------
__global__ void init_readout(unsigned* __restrict__ gmax, float* __restrict__ gsum,
                             int* __restrict__ cnt) {
  int t = threadIdx.x;
  for (int i = t; i < 64 * 64; i += 256) { gmax[i] = 0x007FFFFFu; gsum[i] = 0.f; }
  if (t < 64) cnt[t] = 0;
}

__global__ __launch_bounds__(256) void readout_nodes(const float* __restrict__ h,
    const int* __restrict__ batch, unsigned* __restrict__ gmax,
    float* __restrict__ gsum, int* __restrict__ cnt, int N) {
  int lane = threadIdx.x & 63;
  int n = blockIdx.x * 4 + (threadIdx.x >> 6);
  if (n >= N) return;
  const float* hp = h + (long)n * 256;
  float v = 0.25f * (hp[lane] + hp[64 + lane] + hp[128 + lane] + hp[192 + lane]);
  int b = batch[n];
  atomicMax(&gmax[b * 64 + lane], enc_f(v));
  atomicAdd(&gsum[b * 64 + lane], v);
  if (lane == 0) atomicAdd(&cnt[b], 1);
}

__global__ __launch_bounds__(256) void finalize(const unsigned* __restrict__ gmax,
    const float* __restrict__ gsum, const int* __restrict__ cnt,
    const float* __restrict__ Wout, const float* __restrict__ bout,
    float* __restrict__ out) {
  __shared__ float hid[64 * 192];
  int t = threadIdx.x;
  for (int i = t; i < 64 * 192; i += 256) {
    int b = i / 192, j = i % 192;
    float v;
    if (j < 64) v = dec_f(gmax[b * 64 + j]);
    else if (j < 128) v = gsum[b * 64 + j - 64] / fmaxf((float)cnt[b], 1.f);
    else v = gsum[b * 64 + j - 128];
    hid[i] = v;
    out[1024 + i] = v;  // hidden output (second tuple element)
  }
  __syncthreads();
  for (int i = t; i < 64 * 16; i += 256) {
    int b = i >> 4, o = i & 15;
    float s = bout[o];
    for (int k = 0; k < 192; ++k) s += hid[b * 192 + k] * Wout[k * 16 + o];
    out[i] = s;  // out (first tuple element)
  }
}

extern "C" void kernel_launch(void* const* d_in, const int* in_sizes, int n_in,
                              void* d_out, int out_size, void* d_ws, size_t ws_size,
                              hipStream_t stream) {
  const float* x     = (const float*)d_in[0];
  const int*   ei    = (const int*)d_in[1];
  const int*   batch = (const int*)d_in[2];
  const float* W[3]  = {(const float*)d_in[3], (const float*)d_in[7], (const float*)d_in[11]};
  const float* as_[3] = {(const float*)d_in[4], (const float*)d_in[8], (const float*)d_in[12]};
  const float* ad_[3] = {(const float*)d_in[5], (const float*)d_in[9], (const float*)d_in[13]};
  const float* bb[3] = {(const float*)d_in[6], (const float*)d_in[10], (const float*)d_in[14]};
  const float* Wout  = (const float*)d_in[15];
  const float* bout  = (const float*)d_in[16];
  float* out = (float*)d_out;

  int N    = in_sizes[2];
  int Fin  = in_sizes[0] / N;
  int E    = in_sizes[1] / 2;
  int Etot = E + N;

  char* ws = (char*)d_ws;
  size_t off = 0;
  auto alloc = [&](size_t bytes) -> void* {
    void* p = ws + off;
    off += bytes;
    off = (off + 255) & ~(size_t)255;
    return p;
  };
  float* hA       = (float*)alloc((size_t)N * 256 * 4);
  float* hB       = (float*)alloc((size_t)N * 256 * 4);
  float* a_src    = (float*)alloc((size_t)N * 4 * 4);
  float* a_dst    = (float*)alloc((size_t)N * 4 * 4);
  int* counts     = (int*)alloc((size_t)N * 4);
  int* row_start  = (int*)alloc((size_t)(N + 1) * 4);
  int* write_ptr  = (int*)alloc((size_t)N * 4);
  int* edge_src   = (int*)alloc((size_t)Etot * 4);
  int* chunkSum   = (int*)alloc(64 * 4);
  int* chunkOff   = (int*)alloc(64 * 4);
  unsigned* gmax  = (unsigned*)alloc(64 * 64 * 4);
  float* gsum     = (float*)alloc(64 * 64 * 4);
  int* cnt        = (int*)alloc(64 * 4);

  // ---- CSR build (dst buckets, self-loops appended) ----
  hipMemsetAsync(counts, 0, (size_t)N * 4, stream);
  int nb = (N + 2047) / 2048;
  count_deg<<<(Etot + 255) / 256, 256, 0, stream>>>(ei, E, N, counts);
  chunk_sum<<<nb, 256, 0, stream>>>(counts, chunkSum, N);
  scan_chunks<<<1, 64, 0, stream>>>(chunkSum, chunkOff, nb, row_start, N, Etot);
  scan_emit<<<nb, 256, 0, stream>>>(counts, chunkOff, row_start, write_ptr, N);
  scatter_edges<<<(Etot + 255) / 256, 256, 0, stream>>>(ei, E, N, write_ptr, edge_src);

  // ---- 3 GAT layers ----
  const float* hin = x;
  int K = Fin;
  for (int l = 0; l < 3; ++l) {
    dim3 gg(4, (N + 63) / 64);
    gemm_f32<<<gg, 256, 0, stream>>>(hin, W[l], hB, N, K);
    attn_dot<<<(N + 3) / 4, 256, 0, stream>>>(hB, as_[l], ad_[l], a_src, a_dst, N);
    attn_agg<<<(N + 3) / 4, 256, 0, stream>>>(hB, a_src, a_dst, row_start, edge_src,
                                              bb[l], hA, N);
    hin = hA;
    K = 256;
  }

  // ---- readout ----
  init_readout<<<1, 256, 0, stream>>>(gmax, gsum, cnt);
  readout_nodes<<<(N + 3) / 4, 256, 0, stream>>>(hA, batch, gmax, gsum, cnt, N);
  finalize<<<1, 256, 0, stream>>>(gmax, gsum, cnt, Wout, bout, out);
}

// Round 2
// 793.326 us; speedup vs baseline: 1.7271x; 1.7271x over previous
//
#include <hip/hip_runtime.h>
#include <cfloat>
#include <cmath>

#define NEG_SLOPE 0.2f
#define SOFT_EPS 1e-16f

typedef __bf16 bf16_t;
typedef bf16_t bf16x8 __attribute__((ext_vector_type(8)));
typedef float floatx4 __attribute__((ext_vector_type(4)));

__device__ __forceinline__ float leaky(float x) { return x > 0.f ? x : NEG_SLOPE * x; }

__device__ __forceinline__ unsigned short f2bf(float f) {
  unsigned u = __float_as_uint(f);
  unsigned r = u + 0x7fffu + ((u >> 16) & 1u);   // round-to-nearest-even
  return (unsigned short)(r >> 16);
}

// order-monotonic encoding of float into unsigned (for hardware atomicMax)
__device__ __forceinline__ unsigned enc_f(float f) {
  unsigned u = __float_as_uint(f);
  return (u & 0x80000000u) ? ~u : (u | 0x80000000u);
}
__device__ __forceinline__ float dec_f(unsigned e) {
  unsigned u = (e & 0x80000000u) ? (e ^ 0x80000000u) : ~e;
  return __uint_as_float(u);
}

// ---------------- CSR build ----------------
__global__ void count_deg(const int* __restrict__ ei, int E, int N, int* __restrict__ counts) {
  int e = blockIdx.x * blockDim.x + threadIdx.x;
  int Etot = E + N;
  if (e >= Etot) return;
  int d = (e < E) ? ei[E + e] : (e - E);
  atomicAdd(&counts[d], 1);
}

__global__ __launch_bounds__(256) void chunk_sum(const int* __restrict__ counts,
                                                 int* __restrict__ chunkSum, int N) {
  __shared__ int sc[256];
  int b = blockIdx.x, t = threadIdx.x;
  int base = b * 2048 + t * 8;
  int s = 0;
#pragma unroll
  for (int i = 0; i < 8; ++i) { int idx = base + i; if (idx < N) s += counts[idx]; }
  sc[t] = s; __syncthreads();
  for (int o = 128; o > 0; o >>= 1) { if (t < o) sc[t] += sc[t + o]; __syncthreads(); }
  if (t == 0) chunkSum[b] = sc[0];
}

__global__ void scan_chunks(const int* __restrict__ chunkSum, int* __restrict__ chunkOff,
                            int nb, int* __restrict__ row_start, int N, int Etot) {
  if (threadIdx.x == 0 && blockIdx.x == 0) {
    int r = 0;
    for (int b = 0; b < nb; ++b) { chunkOff[b] = r; r += chunkSum[b]; }
    row_start[N] = Etot;
  }
}

__global__ __launch_bounds__(256) void scan_emit(const int* __restrict__ counts,
    const int* __restrict__ chunkOff, int* __restrict__ row_start,
    int* __restrict__ write_ptr, int N) {
  __shared__ int sc[256];
  int b = blockIdx.x, t = threadIdx.x;
  int base = b * 2048 + t * 8;
  int v[8]; int s = 0;
#pragma unroll
  for (int i = 0; i < 8; ++i) { int idx = base + i; v[i] = (idx < N) ? counts[idx] : 0; s += v[i]; }
  sc[t] = s; __syncthreads();
  for (int o = 1; o < 256; o <<= 1) {
    int x = (t >= o) ? sc[t - o] : 0;
    __syncthreads();
    sc[t] += x;
    __syncthreads();
  }
  int run = chunkOff[b] + sc[t] - s;
#pragma unroll
  for (int i = 0; i < 8; ++i) {
    int idx = base + i;
    if (idx < N) { row_start[idx] = run; write_ptr[idx] = run; }
    run += v[i];
  }
}

__global__ void scatter_edges(const int* __restrict__ ei, int E, int N,
                              int* __restrict__ write_ptr, int* __restrict__ edge_src) {
  int e = blockIdx.x * blockDim.x + threadIdx.x;
  int Etot = E + N;
  if (e >= Etot) return;
  int s, d;
  if (e < E) { s = ei[e]; d = ei[E + e]; } else { s = e - E; d = e - E; }
  int pos = atomicAdd(&write_ptr[d], 1);
  edge_src[pos] = s;
}

// ---------------- dtype conversion ----------------
__global__ __launch_bounds__(256) void cvt_bf16(const float* __restrict__ in,
                                                unsigned short* __restrict__ out, int n4) {
  int i = blockIdx.x * 256 + threadIdx.x;
  if (i >= n4) return;
  float4 v = ((const float4*)in)[i];
  ushort4 o;
  o.x = f2bf(v.x); o.y = f2bf(v.y); o.z = f2bf(v.z); o.w = f2bf(v.w);
  ((ushort4*)out)[i] = o;
}

// W[K][256] -> Wt_bf16[256][K]
__global__ __launch_bounds__(256) void cvt_wt(const float* __restrict__ W,
                                              unsigned short* __restrict__ Wt, int K) {
  int tx = threadIdx.x & 15, ty = threadIdx.x >> 4;
  int k = blockIdx.x * 16 + tx;
  int n = blockIdx.y * 16 + ty;
  if (k < K) Wt[(size_t)n * K + k] = f2bf(W[(size_t)k * 256 + n]);
}

// ---------------- MFMA GEMM: C[N,256] = A[N,K](bf16) * Bt[256,K](bf16)^T ----------------
#define BM 128
#define BN 128
#define BKG 64
#define LDK 72   // padded LDS K-stride (bf16 elems): bank advance 4/row, 2-way max

__global__ __launch_bounds__(256) void gemm_bf16(const unsigned short* __restrict__ A,
    const unsigned short* __restrict__ Bt, float* __restrict__ C, int N, int K) {
  __shared__ unsigned short As[BM][LDK];
  __shared__ unsigned short Bs[BN][LDK];
  int t = threadIdx.x;
  int wave = t >> 6, lane = t & 63;
  int wm = wave & 1, wn = wave >> 1;     // 2x2 wave grid over 128x128 tile
  int row0 = blockIdx.y * BM;
  int col0 = blockIdx.x * BN;
  floatx4 acc[4][4] = {};                // 64x64 per wave: 4x4 tiles of 16x16

  for (int k0 = 0; k0 < K; k0 += BKG) {
#pragma unroll
    for (int i = 0; i < 4; ++i) {
      int idx = t + 256 * i;             // 0..1023
      int m = idx >> 3;                  // 0..127
      int kk = (idx & 7) * 8;            // 0..56
      int r = row0 + m;
      uint4 v = make_uint4(0u, 0u, 0u, 0u);
      if (r < N) v = *(const uint4*)(A + (size_t)r * K + k0 + kk);
      *(uint4*)(&As[m][kk]) = v;
    }
#pragma unroll
    for (int i = 0; i < 4; ++i) {
      int idx = t + 256 * i;
      int n = idx >> 3;
      int kk = (idx & 7) * 8;
      uint4 v = *(const uint4*)(Bt + (size_t)(col0 + n) * K + k0 + kk);
      *(uint4*)(&Bs[n][kk]) = v;
    }
    __syncthreads();
    int mrow = lane & 15;
    int kq = (lane >> 4) * 8;
#pragma unroll
    for (int ks = 0; ks < BKG; ks += 32) {
      bf16x8 af[4], bfr[4];
#pragma unroll
      for (int i = 0; i < 4; ++i)
        af[i] = *(const bf16x8*)(&As[wm * 64 + i * 16 + mrow][kq + ks]);
#pragma unroll
      for (int j = 0; j < 4; ++j)
        bfr[j] = *(const bf16x8*)(&Bs[wn * 64 + j * 16 + mrow][kq + ks]);
#pragma unroll
      for (int i = 0; i < 4; ++i)
#pragma unroll
        for (int j = 0; j < 4; ++j)
          acc[i][j] = __builtin_amdgcn_mfma_f32_16x16x32_bf16(af[i], bfr[j], acc[i][j], 0, 0, 0);
    }
    __syncthreads();
  }
  // C/D layout: col = lane&15, row = (lane>>4)*4 + reg
#pragma unroll
  for (int i = 0; i < 4; ++i) {
    int rb = row0 + wm * 64 + i * 16 + (lane >> 4) * 4;
#pragma unroll
    for (int j = 0; j < 4; ++j) {
      int c = col0 + wn * 64 + j * 16 + (lane & 15);
#pragma unroll
      for (int reg = 0; reg < 4; ++reg) {
        int r = rb + reg;
        if (r < N) C[(size_t)r * 256 + c] = acc[i][j][reg];
      }
    }
  }
}

// ---------------- attention dot: a_src[n,h], a_dst[n,h] ----------------
__global__ __launch_bounds__(256) void attn_dot(const float* __restrict__ g,
    const float* __restrict__ atts, const float* __restrict__ attd,
    float* __restrict__ a_src, float* __restrict__ a_dst, int N) {
  int lane = threadIdx.x & 63;
  int n = blockIdx.x * 4 + (threadIdx.x >> 6);
  if (n >= N) return;
  float4 gv = *(const float4*)(g + (long)n * 256 + lane * 4);
  float4 s4 = *(const float4*)(atts + lane * 4);
  float4 d4 = *(const float4*)(attd + lane * 4);
  float ds = gv.x * s4.x + gv.y * s4.y + gv.z * s4.z + gv.w * s4.w;
  float dd = gv.x * d4.x + gv.y * d4.y + gv.z * d4.z + gv.w * d4.w;
  for (int m = 1; m < 16; m <<= 1) {
    ds += __shfl_xor(ds, m, 64);
    dd += __shfl_xor(dd, m, 64);
  }
  if ((lane & 15) == 0) {
    a_src[n * 4 + (lane >> 4)] = ds;
    a_dst[n * 4 + (lane >> 4)] = dd;
  }
}

// ---------------- per-dst softmax + aggregate + bias + tanh ----------------
__global__ __launch_bounds__(256) void attn_agg(const float* __restrict__ g,
    const float* __restrict__ a_src, const float* __restrict__ a_dst,
    const int* __restrict__ row_start, const int* __restrict__ edge_src,
    const float* __restrict__ bias, float* __restrict__ hout,
    unsigned short* __restrict__ hout_bf, int N) {
  int lane = threadIdx.x & 63;
  int n = blockIdx.x * 4 + (threadIdx.x >> 6);
  if (n >= N) return;
  int beg = row_start[n], end = row_start[n + 1];
  int hof = lane >> 4;
  float ad0 = a_dst[n * 4 + 0], ad1 = a_dst[n * 4 + 1];
  float ad2 = a_dst[n * 4 + 2], ad3 = a_dst[n * 4 + 3];
  float m0 = -FLT_MAX, m1 = -FLT_MAX, m2 = -FLT_MAX, m3 = -FLT_MAX;
  for (int i = beg + lane; i < end; i += 64) {
    const float* as = a_src + (long)edge_src[i] * 4;
    m0 = fmaxf(m0, leaky(as[0] + ad0));
    m1 = fmaxf(m1, leaky(as[1] + ad1));
    m2 = fmaxf(m2, leaky(as[2] + ad2));
    m3 = fmaxf(m3, leaky(as[3] + ad3));
  }
  for (int mm = 1; mm < 64; mm <<= 1) {
    m0 = fmaxf(m0, __shfl_xor(m0, mm, 64));
    m1 = fmaxf(m1, __shfl_xor(m1, mm, 64));
    m2 = fmaxf(m2, __shfl_xor(m2, mm, 64));
    m3 = fmaxf(m3, __shfl_xor(m3, mm, 64));
  }
  float d0 = 0.f, d1 = 0.f, d2 = 0.f, d3 = 0.f;
  for (int i = beg + lane; i < end; i += 64) {
    const float* as = a_src + (long)edge_src[i] * 4;
    d0 += expf(leaky(as[0] + ad0) - m0);
    d1 += expf(leaky(as[1] + ad1) - m1);
    d2 += expf(leaky(as[2] + ad2) - m2);
    d3 += expf(leaky(as[3] + ad3) - m3);
  }
  for (int mm = 1; mm < 64; mm <<= 1) {
    d0 += __shfl_xor(d0, mm, 64);
    d1 += __shfl_xor(d1, mm, 64);
    d2 += __shfl_xor(d2, mm, 64);
    d3 += __shfl_xor(d3, mm, 64);
  }
  float adh = (hof == 0) ? ad0 : (hof == 1) ? ad1 : (hof == 2) ? ad2 : ad3;
  float mh  = (hof == 0) ? m0  : (hof == 1) ? m1  : (hof == 2) ? m2  : m3;
  float dh  = ((hof == 0) ? d0 : (hof == 1) ? d1 : (hof == 2) ? d2 : d3) + SOFT_EPS;
  float4 acc = make_float4(0.f, 0.f, 0.f, 0.f);
  for (int i = beg; i < end; ++i) {
    int s = edge_src[i];
    float e = leaky(a_src[(long)s * 4 + hof] + adh);
    float alpha = expf(e - mh) / dh;
    float4 gv = *(const float4*)(g + (long)s * 256 + lane * 4);
    acc.x += alpha * gv.x; acc.y += alpha * gv.y;
    acc.z += alpha * gv.z; acc.w += alpha * gv.w;
  }
  float4 bv = *(const float4*)(bias + lane * 4);
  float4 o;
  o.x = tanhf(acc.x + bv.x); o.y = tanhf(acc.y + bv.y);
  o.z = tanhf(acc.z + bv.z); o.w = tanhf(acc.w + bv.w);
  *(float4*)(hout + (long)n * 256 + lane * 4) = o;
  ushort4 ob;
  ob.x = f2bf(o.x); ob.y = f2bf(o.y); ob.z = f2bf(o.z); ob.w = f2bf(o.w);
  *(ushort4*)(hout_bf + (long)n * 256 + lane * 4) = ob;
}

// ---------------- readout ----------------
__global__ void init_readout(unsigned* __restrict__ gmax, float* __restrict__ gsum,
                             int* __restrict__ cnt) {
  int t = threadIdx.x;
  for (int i = t; i < 64 * 64; i += 256) { gmax[i] = 0x007FFFFFu; gsum[i] = 0.f; }
  if (t < 64) cnt[t] = 0;
}

// batch_index is sorted: accumulate locally per segment, flush one atomic per boundary.
#define RNPB 256
__global__ __launch_bounds__(256) void readout_nodes(const float* __restrict__ h,
    const int* __restrict__ batch, unsigned* __restrict__ gmax,
    float* __restrict__ gsum, int* __restrict__ cnt, int N) {
  int t = threadIdx.x;
  int c = t & 63;
  int q = t >> 6;
  int n0 = blockIdx.x * RNPB + q * (RNPB / 4);
  if (n0 >= N) return;
  int n1 = min(n0 + RNPB / 4, N);
  float vmax = -FLT_MAX, vsum = 0.f;
  int curb = batch[n0];
  int cl = 0;
  for (int n = n0; n < n1; ++n) {
    int b = batch[n];
    if (b != curb) {
      atomicMax(&gmax[curb * 64 + c], enc_f(vmax));
      atomicAdd(&gsum[curb * 64 + c], vsum);
      if (c == 0) atomicAdd(&cnt[curb], cl);
      vmax = -FLT_MAX; vsum = 0.f; cl = 0; curb = b;
    }
    const float* hp = h + (size_t)n * 256;
    float v = 0.25f * (hp[c] + hp[64 + c] + hp[128 + c] + hp[192 + c]);
    vmax = fmaxf(vmax, v); vsum += v; ++cl;
  }
  atomicMax(&gmax[curb * 64 + c], enc_f(vmax));
  atomicAdd(&gsum[curb * 64 + c], vsum);
  if (c == 0) atomicAdd(&cnt[curb], cl);
}

__global__ __launch_bounds__(256) void finalize(const unsigned* __restrict__ gmax,
    const float* __restrict__ gsum, const int* __restrict__ cnt,
    const float* __restrict__ Wout, const float* __restrict__ bout,
    float* __restrict__ out) {
  __shared__ float hid[64 * 192];
  int t = threadIdx.x;
  for (int i = t; i < 64 * 192; i += 256) {
    int b = i / 192, j = i % 192;
    float v;
    if (j < 64) v = dec_f(gmax[b * 64 + j]);
    else if (j < 128) v = gsum[b * 64 + j - 64] / fmaxf((float)cnt[b], 1.f);
    else v = gsum[b * 64 + j - 128];
    hid[i] = v;
    out[1024 + i] = v;
  }
  __syncthreads();
  for (int i = t; i < 64 * 16; i += 256) {
    int b = i >> 4, o = i & 15;
    float s = bout[o];
    for (int k = 0; k < 192; ++k) s += hid[b * 192 + k] * Wout[k * 16 + o];
    out[i] = s;
  }
}

extern "C" void kernel_launch(void* const* d_in, const int* in_sizes, int n_in,
                              void* d_out, int out_size, void* d_ws, size_t ws_size,
                              hipStream_t stream) {
  const float* x     = (const float*)d_in[0];
  const int*   ei    = (const int*)d_in[1];
  const int*   batch = (const int*)d_in[2];
  const float* W[3]  = {(const float*)d_in[3], (const float*)d_in[7], (const float*)d_in[11]};
  const float* as_[3] = {(const float*)d_in[4], (const float*)d_in[8], (const float*)d_in[12]};
  const float* ad_[3] = {(const float*)d_in[5], (const float*)d_in[9], (const float*)d_in[13]};
  const float* bb[3] = {(const float*)d_in[6], (const float*)d_in[10], (const float*)d_in[14]};
  const float* Wout  = (const float*)d_in[15];
  const float* bout  = (const float*)d_in[16];
  float* out = (float*)d_out;

  int N    = in_sizes[2];
  int Fin  = in_sizes[0] / N;
  int E    = in_sizes[1] / 2;
  int Etot = E + N;

  char* ws = (char*)d_ws;
  size_t off = 0;
  auto alloc = [&](size_t bytes) -> void* {
    void* p = ws + off;
    off += bytes;
    off = (off + 255) & ~(size_t)255;
    return p;
  };
  float* hA       = (float*)alloc((size_t)N * 256 * 4);   // attn_agg out (fp32, readout)
  float* hB       = (float*)alloc((size_t)N * 256 * 4);   // gemm out
  unsigned short* hbf = (unsigned short*)alloc((size_t)N * 256 * 2);  // bf16 gemm input
  unsigned short* Wt[3];
  Wt[0] = (unsigned short*)alloc((size_t)256 * Fin * 2);
  Wt[1] = (unsigned short*)alloc((size_t)256 * 256 * 2);
  Wt[2] = (unsigned short*)alloc((size_t)256 * 256 * 2);
  float* a_src    = (float*)alloc((size_t)N * 4 * 4);
  float* a_dst    = (float*)alloc((size_t)N * 4 * 4);
  int* counts     = (int*)alloc((size_t)N * 4);
  int* row_start  = (int*)alloc((size_t)(N + 1) * 4);
  int* write_ptr  = (int*)alloc((size_t)N * 4);
  int* edge_src   = (int*)alloc((size_t)Etot * 4);
  int* chunkSum   = (int*)alloc(64 * 4);
  int* chunkOff   = (int*)alloc(64 * 4);
  unsigned* gmax  = (unsigned*)alloc(64 * 64 * 4);
  float* gsum     = (float*)alloc(64 * 64 * 4);
  int* cnt        = (int*)alloc(64 * 4);

  // ---- CSR build ----
  hipMemsetAsync(counts, 0, (size_t)N * 4, stream);
  int nb = (N + 2047) / 2048;
  count_deg<<<(Etot + 255) / 256, 256, 0, stream>>>(ei, E, N, counts);
  chunk_sum<<<nb, 256, 0, stream>>>(counts, chunkSum, N);
  scan_chunks<<<1, 64, 0, stream>>>(chunkSum, chunkOff, nb, row_start, N, Etot);
  scan_emit<<<nb, 256, 0, stream>>>(counts, chunkOff, row_start, write_ptr, N);
  scatter_edges<<<(Etot + 255) / 256, 256, 0, stream>>>(ei, E, N, write_ptr, edge_src);

  // ---- weight transpose-convert, x convert ----
  cvt_wt<<<dim3((Fin + 15) / 16, 16), 256, 0, stream>>>(W[0], Wt[0], Fin);
  cvt_wt<<<dim3(16, 16), 256, 0, stream>>>(W[1], Wt[1], 256);
  cvt_wt<<<dim3(16, 16), 256, 0, stream>>>(W[2], Wt[2], 256);
  cvt_bf16<<<((N * Fin / 4) + 255) / 256, 256, 0, stream>>>(x, hbf, N * Fin / 4);

  // ---- 3 GAT layers ----
  int K = Fin;
  for (int l = 0; l < 3; ++l) {
    dim3 gg(2, (N + BM - 1) / BM);
    gemm_bf16<<<gg, 256, 0, stream>>>(hbf, Wt[l], hB, N, K);
    attn_dot<<<(N + 3) / 4, 256, 0, stream>>>(hB, as_[l], ad_[l], a_src, a_dst, N);
    attn_agg<<<(N + 3) / 4, 256, 0, stream>>>(hB, a_src, a_dst, row_start, edge_src,
                                              bb[l], hA, hbf, N);
    K = 256;
  }

  // ---- readout ----
  init_readout<<<1, 256, 0, stream>>>(gmax, gsum, cnt);
  readout_nodes<<<(N + RNPB - 1) / RNPB, 256, 0, stream>>>(hA, batch, gmax, gsum, cnt, N);
  finalize<<<1, 256, 0, stream>>>(gmax, gsum, cnt, Wout, bout, out);
}

// Round 3
// 692.122 us; speedup vs baseline: 1.9797x; 1.1462x over previous
//
#include <hip/hip_runtime.h>
#include <cfloat>
#include <cmath>

#define NEG_SLOPE 0.2f
#define SOFT_EPS 1e-16f

typedef __bf16 bf16_t;
typedef bf16_t bf16x8 __attribute__((ext_vector_type(8)));
typedef float floatx4 __attribute__((ext_vector_type(4)));

__device__ __forceinline__ float leaky(float x) { return x > 0.f ? x : NEG_SLOPE * x; }

__device__ __forceinline__ unsigned short f2bf(float f) {
  unsigned u = __float_as_uint(f);
  unsigned r = u + 0x7fffu + ((u >> 16) & 1u);   // round-to-nearest-even
  return (unsigned short)(r >> 16);
}
__device__ __forceinline__ float bf2f(unsigned short b) {
  return __uint_as_float((unsigned)b << 16);
}

// order-monotonic encoding of float into unsigned (for hardware atomicMax)
__device__ __forceinline__ unsigned enc_f(float f) {
  unsigned u = __float_as_uint(f);
  return (u & 0x80000000u) ? ~u : (u | 0x80000000u);
}
__device__ __forceinline__ float dec_f(unsigned e) {
  unsigned u = (e & 0x80000000u) ? (e ^ 0x80000000u) : ~e;
  return __uint_as_float(u);
}

// ---------------- CSR build ----------------
__global__ void count_deg(const int* __restrict__ ei, int E, int N, int* __restrict__ counts) {
  int e = blockIdx.x * blockDim.x + threadIdx.x;
  int Etot = E + N;
  if (e >= Etot) return;
  int d = (e < E) ? ei[E + e] : (e - E);
  atomicAdd(&counts[d], 1);
}

__global__ __launch_bounds__(256) void chunk_sum(const int* __restrict__ counts,
                                                 int* __restrict__ chunkSum, int N) {
  __shared__ int sc[256];
  int b = blockIdx.x, t = threadIdx.x;
  int base = b * 2048 + t * 8;
  int s = 0;
#pragma unroll
  for (int i = 0; i < 8; ++i) { int idx = base + i; if (idx < N) s += counts[idx]; }
  sc[t] = s; __syncthreads();
  for (int o = 128; o > 0; o >>= 1) { if (t < o) sc[t] += sc[t + o]; __syncthreads(); }
  if (t == 0) chunkSum[b] = sc[0];
}

__global__ void scan_chunks(const int* __restrict__ chunkSum, int* __restrict__ chunkOff,
                            int nb, int* __restrict__ row_start, int N, int Etot) {
  if (threadIdx.x == 0 && blockIdx.x == 0) {
    int r = 0;
    for (int b = 0; b < nb; ++b) { chunkOff[b] = r; r += chunkSum[b]; }
    row_start[N] = Etot;
  }
}

__global__ __launch_bounds__(256) void scan_emit(const int* __restrict__ counts,
    const int* __restrict__ chunkOff, int* __restrict__ row_start,
    int* __restrict__ write_ptr, int N) {
  __shared__ int sc[256];
  int b = blockIdx.x, t = threadIdx.x;
  int base = b * 2048 + t * 8;
  int v[8]; int s = 0;
#pragma unroll
  for (int i = 0; i < 8; ++i) { int idx = base + i; v[i] = (idx < N) ? counts[idx] : 0; s += v[i]; }
  sc[t] = s; __syncthreads();
  for (int o = 1; o < 256; o <<= 1) {
    int x = (t >= o) ? sc[t - o] : 0;
    __syncthreads();
    sc[t] += x;
    __syncthreads();
  }
  int run = chunkOff[b] + sc[t] - s;
#pragma unroll
  for (int i = 0; i < 8; ++i) {
    int idx = base + i;
    if (idx < N) { row_start[idx] = run; write_ptr[idx] = run; }
    run += v[i];
  }
}

__global__ void scatter_edges(const int* __restrict__ ei, int E, int N,
                              int* __restrict__ write_ptr, int* __restrict__ edge_src) {
  int e = blockIdx.x * blockDim.x + threadIdx.x;
  int Etot = E + N;
  if (e >= Etot) return;
  int s, d;
  if (e < E) { s = ei[e]; d = ei[E + e]; } else { s = e - E; d = e - E; }
  int pos = atomicAdd(&write_ptr[d], 1);
  edge_src[pos] = s;
}

// ---------------- dtype conversion ----------------
__global__ __launch_bounds__(256) void cvt_bf16(const float* __restrict__ in,
                                                unsigned short* __restrict__ out, int n4) {
  int i = blockIdx.x * 256 + threadIdx.x;
  if (i >= n4) return;
  float4 v = ((const float4*)in)[i];
  ushort4 o;
  o.x = f2bf(v.x); o.y = f2bf(v.y); o.z = f2bf(v.z); o.w = f2bf(v.w);
  ((ushort4*)out)[i] = o;
}

// W[K][256] -> Wt_bf16[256][K]
__global__ __launch_bounds__(256) void cvt_wt(const float* __restrict__ W,
                                              unsigned short* __restrict__ Wt, int K) {
  int tx = threadIdx.x & 15, ty = threadIdx.x >> 4;
  int k = blockIdx.x * 16 + tx;
  int n = blockIdx.y * 16 + ty;
  if (k < K) Wt[(size_t)n * K + k] = f2bf(W[(size_t)k * 256 + n]);
}

// ---- MFMA GEMM + fused attention dots:
//   Cbf[N,256](bf16) = A[N,K](bf16) * Bt[256,K]^T
//   a_src[r][head] = sum_c C[r][head*64+c]*attS[head][c]   (same for a_dst)
#define BM 128
#define BN 128
#define BKG 64
#define LDK 72   // padded LDS K-stride (bf16): 2-way bank aliasing max (free)

__global__ __launch_bounds__(256) void gemm_bf16(const unsigned short* __restrict__ A,
    const unsigned short* __restrict__ Bt, unsigned short* __restrict__ Cbf,
    float* __restrict__ a_src, float* __restrict__ a_dst,
    const float* __restrict__ attS, const float* __restrict__ attD, int N, int K) {
  __shared__ unsigned short As[BM][LDK];
  __shared__ unsigned short Bs[BN][LDK];
  int t = threadIdx.x;
  int wave = t >> 6, lane = t & 63;
  int wm = wave & 1, wn = wave >> 1;
  int row0 = blockIdx.y * BM;
  int col0 = blockIdx.x * BN;
  floatx4 acc[4][4] = {};

  for (int k0 = 0; k0 < K; k0 += BKG) {
#pragma unroll
    for (int i = 0; i < 4; ++i) {
      int idx = t + 256 * i;
      int m = idx >> 3;
      int kk = (idx & 7) * 8;
      int r = row0 + m;
      uint4 v = make_uint4(0u, 0u, 0u, 0u);
      if (r < N) v = *(const uint4*)(A + (size_t)r * K + k0 + kk);
      *(uint4*)(&As[m][kk]) = v;
    }
#pragma unroll
    for (int i = 0; i < 4; ++i) {
      int idx = t + 256 * i;
      int n = idx >> 3;
      int kk = (idx & 7) * 8;
      uint4 v = *(const uint4*)(Bt + (size_t)(col0 + n) * K + k0 + kk);
      *(uint4*)(&Bs[n][kk]) = v;
    }
    __syncthreads();
    int mrow = lane & 15;
    int kq = (lane >> 4) * 8;
#pragma unroll
    for (int ks = 0; ks < BKG; ks += 32) {
      bf16x8 af[4], bfr[4];
#pragma unroll
      for (int i = 0; i < 4; ++i)
        af[i] = *(const bf16x8*)(&As[wm * 64 + i * 16 + mrow][kq + ks]);
#pragma unroll
      for (int j = 0; j < 4; ++j)
        bfr[j] = *(const bf16x8*)(&Bs[wn * 64 + j * 16 + mrow][kq + ks]);
#pragma unroll
      for (int i = 0; i < 4; ++i)
#pragma unroll
        for (int j = 0; j < 4; ++j)
          acc[i][j] = __builtin_amdgcn_mfma_f32_16x16x32_bf16(af[i], bfr[j], acc[i][j], 0, 0, 0);
    }
    __syncthreads();
  }

  // C store (bf16). C/D layout: col = lane&15, row = (lane>>4)*4 + reg
#pragma unroll
  for (int i = 0; i < 4; ++i) {
    int rb = row0 + wm * 64 + i * 16 + (lane >> 4) * 4;
#pragma unroll
    for (int j = 0; j < 4; ++j) {
      int c = col0 + wn * 64 + j * 16 + (lane & 15);
#pragma unroll
      for (int reg = 0; reg < 4; ++reg) {
        int r = rb + reg;
        if (r < N) Cbf[(size_t)r * 256 + c] = f2bf(acc[i][j][reg]);
      }
    }
  }

  // fused attention dots: this wave owns head = bx*2+wn, 64 rows (wm half)
  int head = blockIdx.x * 2 + wn;
  int cin = lane & 15;
  float aS[4], aD[4];
#pragma unroll
  for (int j = 0; j < 4; ++j) {
    aS[j] = attS[head * 64 + j * 16 + cin];
    aD[j] = attD[head * 64 + j * 16 + cin];
  }
#pragma unroll
  for (int i = 0; i < 4; ++i) {
    floatx4 ps = {0.f, 0.f, 0.f, 0.f}, pd = {0.f, 0.f, 0.f, 0.f};
#pragma unroll
    for (int j = 0; j < 4; ++j) {
      ps += acc[i][j] * aS[j];
      pd += acc[i][j] * aD[j];
    }
#pragma unroll
    for (int m = 1; m < 16; m <<= 1) {
#pragma unroll
      for (int k = 0; k < 4; ++k) {
        ps[k] += __shfl_xor(ps[k], m, 64);
        pd[k] += __shfl_xor(pd[k], m, 64);
      }
    }
    if ((lane & 15) == 0) {
      int rb = row0 + wm * 64 + i * 16 + (lane >> 4) * 4;
#pragma unroll
      for (int reg = 0; reg < 4; ++reg) {
        int r = rb + reg;
        if (r < N) {
          a_src[r * 4 + head] = ps[reg];
          a_dst[r * 4 + head] = pd[reg];
        }
      }
    }
  }
}

// ---------------- per-dst softmax + aggregate + bias + tanh ----------------
// g is bf16 [N][256]. No max pass (values bounded; clamp at 60 for safety).
__global__ __launch_bounds__(256) void attn_agg(const unsigned short* __restrict__ g,
    const float* __restrict__ a_src, const float* __restrict__ a_dst,
    const int* __restrict__ row_start, const int* __restrict__ edge_src,
    const float* __restrict__ bias, float* __restrict__ hout,
    unsigned short* __restrict__ hout_bf, int N) {
  int lane = threadIdx.x & 63;
  int n = blockIdx.x * 4 + (threadIdx.x >> 6);
  if (n >= N) return;
  int beg = row_start[n], end = row_start[n + 1];
  int hof = lane >> 4;
  float ad0 = a_dst[n * 4 + 0], ad1 = a_dst[n * 4 + 1];
  float ad2 = a_dst[n * 4 + 2], ad3 = a_dst[n * 4 + 3];
  // denom pass
  float d0 = 0.f, d1 = 0.f, d2 = 0.f, d3 = 0.f;
  for (int i = beg + lane; i < end; i += 64) {
    const float* as = a_src + (long)edge_src[i] * 4;
    d0 += expf(fminf(leaky(as[0] + ad0), 60.f));
    d1 += expf(fminf(leaky(as[1] + ad1), 60.f));
    d2 += expf(fminf(leaky(as[2] + ad2), 60.f));
    d3 += expf(fminf(leaky(as[3] + ad3), 60.f));
  }
  for (int mm = 1; mm < 64; mm <<= 1) {
    d0 += __shfl_xor(d0, mm, 64);
    d1 += __shfl_xor(d1, mm, 64);
    d2 += __shfl_xor(d2, mm, 64);
    d3 += __shfl_xor(d3, mm, 64);
  }
  float adh = (hof == 0) ? ad0 : (hof == 1) ? ad1 : (hof == 2) ? ad2 : ad3;
  float dh  = ((hof == 0) ? d0 : (hof == 1) ? d1 : (hof == 2) ? d2 : d3) + SOFT_EPS;
  float inv = 1.f / dh;
  // gather pass
  float4 acc = make_float4(0.f, 0.f, 0.f, 0.f);
  for (int i = beg; i < end; ++i) {
    int s = edge_src[i];
    float e = fminf(leaky(a_src[(long)s * 4 + hof] + adh), 60.f);
    float alpha = expf(e) * inv;
    ushort4 gv = *(const ushort4*)(g + (size_t)s * 256 + lane * 4);
    acc.x += alpha * bf2f(gv.x); acc.y += alpha * bf2f(gv.y);
    acc.z += alpha * bf2f(gv.z); acc.w += alpha * bf2f(gv.w);
  }
  float4 bv = *(const float4*)(bias + lane * 4);
  float4 o;
  o.x = tanhf(acc.x + bv.x); o.y = tanhf(acc.y + bv.y);
  o.z = tanhf(acc.z + bv.z); o.w = tanhf(acc.w + bv.w);
  if (hout) *(float4*)(hout + (long)n * 256 + lane * 4) = o;
  if (hout_bf) {
    ushort4 ob;
    ob.x = f2bf(o.x); ob.y = f2bf(o.y); ob.z = f2bf(o.z); ob.w = f2bf(o.w);
    *(ushort4*)(hout_bf + (long)n * 256 + lane * 4) = ob;
  }
}

// ---------------- readout ----------------
__global__ void init_readout(unsigned* __restrict__ gmax, float* __restrict__ gsum,
                             int* __restrict__ cnt) {
  int t = threadIdx.x;
  for (int i = t; i < 64 * 64; i += 256) { gmax[i] = 0x007FFFFFu; gsum[i] = 0.f; }
  if (t < 64) cnt[t] = 0;
}

#define RNPB 256
__global__ __launch_bounds__(256) void readout_nodes(const float* __restrict__ h,
    const int* __restrict__ batch, unsigned* __restrict__ gmax,
    float* __restrict__ gsum, int* __restrict__ cnt, int N) {
  int t = threadIdx.x;
  int c = t & 63;
  int q = t >> 6;
  int n0 = blockIdx.x * RNPB + q * (RNPB / 4);
  if (n0 >= N) return;
  int n1 = min(n0 + RNPB / 4, N);
  float vmax = -FLT_MAX, vsum = 0.f;
  int curb = batch[n0];
  int cl = 0;
  for (int n = n0; n < n1; ++n) {
    int b = batch[n];
    if (b != curb) {
      atomicMax(&gmax[curb * 64 + c], enc_f(vmax));
      atomicAdd(&gsum[curb * 64 + c], vsum);
      if (c == 0) atomicAdd(&cnt[curb], cl);
      vmax = -FLT_MAX; vsum = 0.f; cl = 0; curb = b;
    }
    const float* hp = h + (size_t)n * 256;
    float v = 0.25f * (hp[c] + hp[64 + c] + hp[128 + c] + hp[192 + c]);
    vmax = fmaxf(vmax, v); vsum += v; ++cl;
  }
  atomicMax(&gmax[curb * 64 + c], enc_f(vmax));
  atomicAdd(&gsum[curb * 64 + c], vsum);
  if (c == 0) atomicAdd(&cnt[curb], cl);
}

__global__ __launch_bounds__(256) void finalize(const unsigned* __restrict__ gmax,
    const float* __restrict__ gsum, const int* __restrict__ cnt,
    const float* __restrict__ Wout, const float* __restrict__ bout,
    float* __restrict__ out) {
  __shared__ float hid[64 * 192];
  int t = threadIdx.x;
  for (int i = t; i < 64 * 192; i += 256) {
    int b = i / 192, j = i % 192;
    float v;
    if (j < 64) v = dec_f(gmax[b * 64 + j]);
    else if (j < 128) v = gsum[b * 64 + j - 64] / fmaxf((float)cnt[b], 1.f);
    else v = gsum[b * 64 + j - 128];
    hid[i] = v;
    out[1024 + i] = v;
  }
  __syncthreads();
  for (int i = t; i < 64 * 16; i += 256) {
    int b = i >> 4, o = i & 15;
    float s = bout[o];
    for (int k = 0; k < 192; ++k) s += hid[b * 192 + k] * Wout[k * 16 + o];
    out[i] = s;
  }
}

extern "C" void kernel_launch(void* const* d_in, const int* in_sizes, int n_in,
                              void* d_out, int out_size, void* d_ws, size_t ws_size,
                              hipStream_t stream) {
  const float* x     = (const float*)d_in[0];
  const int*   ei    = (const int*)d_in[1];
  const int*   batch = (const int*)d_in[2];
  const float* W[3]  = {(const float*)d_in[3], (const float*)d_in[7], (const float*)d_in[11]};
  const float* as_[3] = {(const float*)d_in[4], (const float*)d_in[8], (const float*)d_in[12]};
  const float* ad_[3] = {(const float*)d_in[5], (const float*)d_in[9], (const float*)d_in[13]};
  const float* bb[3] = {(const float*)d_in[6], (const float*)d_in[10], (const float*)d_in[14]};
  const float* Wout  = (const float*)d_in[15];
  const float* bout  = (const float*)d_in[16];
  float* out = (float*)d_out;

  int N    = in_sizes[2];
  int Fin  = in_sizes[0] / N;
  int E    = in_sizes[1] / 2;
  int Etot = E + N;

  char* ws = (char*)d_ws;
  size_t off = 0;
  auto alloc = [&](size_t bytes) -> void* {
    void* p = ws + off;
    off += bytes;
    off = (off + 255) & ~(size_t)255;
    return p;
  };
  float* hA        = (float*)alloc((size_t)N * 256 * 4);           // layer-2 fp32 out (readout)
  unsigned short* gbf  = (unsigned short*)alloc((size_t)N * 256 * 2);  // gemm out (bf16)
  unsigned short* h0bf = (unsigned short*)alloc((size_t)N * Fin * 2);  // x (bf16)
  unsigned short* h1bf = (unsigned short*)alloc((size_t)N * 256 * 2);  // layer out (bf16)
  unsigned short* Wt[3];
  Wt[0] = (unsigned short*)alloc((size_t)256 * Fin * 2);
  Wt[1] = (unsigned short*)alloc((size_t)256 * 256 * 2);
  Wt[2] = (unsigned short*)alloc((size_t)256 * 256 * 2);
  float* a_src    = (float*)alloc((size_t)N * 4 * 4);
  float* a_dst    = (float*)alloc((size_t)N * 4 * 4);
  int* counts     = (int*)alloc((size_t)N * 4);
  int* row_start  = (int*)alloc((size_t)(N + 1) * 4);
  int* write_ptr  = (int*)alloc((size_t)N * 4);
  int* edge_src   = (int*)alloc((size_t)Etot * 4);
  int* chunkSum   = (int*)alloc(64 * 4);
  int* chunkOff   = (int*)alloc(64 * 4);
  unsigned* gmax  = (unsigned*)alloc(64 * 64 * 4);
  float* gsum     = (float*)alloc(64 * 64 * 4);
  int* cnt        = (int*)alloc(64 * 4);

  // ---- CSR build ----
  hipMemsetAsync(counts, 0, (size_t)N * 4, stream);
  int nb = (N + 2047) / 2048;
  count_deg<<<(Etot + 255) / 256, 256, 0, stream>>>(ei, E, N, counts);
  chunk_sum<<<nb, 256, 0, stream>>>(counts, chunkSum, N);
  scan_chunks<<<1, 64, 0, stream>>>(chunkSum, chunkOff, nb, row_start, N, Etot);
  scan_emit<<<nb, 256, 0, stream>>>(counts, chunkOff, row_start, write_ptr, N);
  scatter_edges<<<(Etot + 255) / 256, 256, 0, stream>>>(ei, E, N, write_ptr, edge_src);

  // ---- weight transpose-convert, x convert ----
  cvt_wt<<<dim3((Fin + 15) / 16, 16), 256, 0, stream>>>(W[0], Wt[0], Fin);
  cvt_wt<<<dim3(16, 16), 256, 0, stream>>>(W[1], Wt[1], 256);
  cvt_wt<<<dim3(16, 16), 256, 0, stream>>>(W[2], Wt[2], 256);
  cvt_bf16<<<((N * Fin / 4) + 255) / 256, 256, 0, stream>>>(x, h0bf, N * Fin / 4);

  // ---- 3 GAT layers ----
  const unsigned short* Ain = h0bf;
  int K = Fin;
  for (int l = 0; l < 3; ++l) {
    dim3 gg(2, (N + BM - 1) / BM);
    gemm_bf16<<<gg, 256, 0, stream>>>(Ain, Wt[l], gbf, a_src, a_dst, as_[l], ad_[l], N, K);
    attn_agg<<<(N + 3) / 4, 256, 0, stream>>>(gbf, a_src, a_dst, row_start, edge_src,
                                              bb[l],
                                              (l == 2) ? hA : (float*)nullptr,
                                              (l < 2) ? h1bf : (unsigned short*)nullptr, N);
    Ain = h1bf;
    K = 256;
  }

  // ---- readout ----
  init_readout<<<1, 256, 0, stream>>>(gmax, gsum, cnt);
  readout_nodes<<<(N + RNPB - 1) / RNPB, 256, 0, stream>>>(hA, batch, gmax, gsum, cnt, N);
  finalize<<<1, 256, 0, stream>>>(gmax, gsum, cnt, Wout, bout, out);
}

// Round 4
// 576.114 us; speedup vs baseline: 2.3783x; 1.2014x over previous
//
#include <hip/hip_runtime.h>
#include <cfloat>
#include <cmath>

#define NEG_SLOPE 0.2f
#define SOFT_EPS 1e-16f

typedef __bf16 bf16_t;
typedef bf16_t bf16x8 __attribute__((ext_vector_type(8)));
typedef float floatx4 __attribute__((ext_vector_type(4)));

__device__ __forceinline__ float leaky(float x) { return x > 0.f ? x : NEG_SLOPE * x; }

__device__ __forceinline__ unsigned short f2bf(float f) {
  unsigned u = __float_as_uint(f);
  unsigned r = u + 0x7fffu + ((u >> 16) & 1u);   // round-to-nearest-even
  return (unsigned short)(r >> 16);
}
__device__ __forceinline__ float bflo(unsigned u) { return __uint_as_float(u << 16); }
__device__ __forceinline__ float bfhi(unsigned u) { return __uint_as_float(u & 0xffff0000u); }

// order-monotonic encoding of float into unsigned (for hardware atomicMax)
__device__ __forceinline__ unsigned enc_f(float f) {
  unsigned u = __float_as_uint(f);
  return (u & 0x80000000u) ? ~u : (u | 0x80000000u);
}
__device__ __forceinline__ float dec_f(unsigned e) {
  unsigned u = (e & 0x80000000u) ? (e ^ 0x80000000u) : ~e;
  return __uint_as_float(u);
}

// ---------------- CSR build ----------------
__global__ void count_deg(const int* __restrict__ ei, int E, int N, int* __restrict__ counts) {
  int e = blockIdx.x * blockDim.x + threadIdx.x;
  int Etot = E + N;
  if (e >= Etot) return;
  int d = (e < E) ? ei[E + e] : (e - E);
  atomicAdd(&counts[d], 1);
}

__global__ __launch_bounds__(256) void chunk_sum(const int* __restrict__ counts,
                                                 int* __restrict__ chunkSum, int N) {
  __shared__ int sc[256];
  int b = blockIdx.x, t = threadIdx.x;
  int base = b * 2048 + t * 8;
  int s = 0;
#pragma unroll
  for (int i = 0; i < 8; ++i) { int idx = base + i; if (idx < N) s += counts[idx]; }
  sc[t] = s; __syncthreads();
  for (int o = 128; o > 0; o >>= 1) { if (t < o) sc[t] += sc[t + o]; __syncthreads(); }
  if (t == 0) chunkSum[b] = sc[0];
}

__global__ void scan_chunks(const int* __restrict__ chunkSum, int* __restrict__ chunkOff,
                            int nb, int* __restrict__ row_start, int N, int Etot) {
  if (threadIdx.x == 0 && blockIdx.x == 0) {
    int r = 0;
    for (int b = 0; b < nb; ++b) { chunkOff[b] = r; r += chunkSum[b]; }
    row_start[N] = Etot;
  }
}

__global__ __launch_bounds__(256) void scan_emit(const int* __restrict__ counts,
    const int* __restrict__ chunkOff, int* __restrict__ row_start,
    int* __restrict__ write_ptr, int N) {
  __shared__ int sc[256];
  int b = blockIdx.x, t = threadIdx.x;
  int base = b * 2048 + t * 8;
  int v[8]; int s = 0;
#pragma unroll
  for (int i = 0; i < 8; ++i) { int idx = base + i; v[i] = (idx < N) ? counts[idx] : 0; s += v[i]; }
  sc[t] = s; __syncthreads();
  for (int o = 1; o < 256; o <<= 1) {
    int x = (t >= o) ? sc[t - o] : 0;
    __syncthreads();
    sc[t] += x;
    __syncthreads();
  }
  int run = chunkOff[b] + sc[t] - s;
#pragma unroll
  for (int i = 0; i < 8; ++i) {
    int idx = base + i;
    if (idx < N) { row_start[idx] = run; write_ptr[idx] = run; }
    run += v[i];
  }
}

__global__ void scatter_edges(const int* __restrict__ ei, int E, int N,
                              int* __restrict__ write_ptr, int* __restrict__ edge_src,
                              int* __restrict__ edge_dst) {
  int e = blockIdx.x * blockDim.x + threadIdx.x;
  int Etot = E + N;
  if (e >= Etot) return;
  int s, d;
  if (e < E) { s = ei[e]; d = ei[E + e]; } else { s = e - E; d = e - E; }
  int pos = atomicAdd(&write_ptr[d], 1);
  edge_src[pos] = s;
  edge_dst[pos] = d;
}

// ---------------- dtype conversion ----------------
__global__ __launch_bounds__(256) void cvt_bf16(const float* __restrict__ in,
                                                unsigned short* __restrict__ out, int n4) {
  int i = blockIdx.x * 256 + threadIdx.x;
  if (i >= n4) return;
  float4 v = ((const float4*)in)[i];
  ushort4 o;
  o.x = f2bf(v.x); o.y = f2bf(v.y); o.z = f2bf(v.z); o.w = f2bf(v.w);
  ((ushort4*)out)[i] = o;
}

// W[K][256] -> Wt_bf16[256][K]
__global__ __launch_bounds__(256) void cvt_wt(const float* __restrict__ W,
                                              unsigned short* __restrict__ Wt, int K) {
  int tx = threadIdx.x & 15, ty = threadIdx.x >> 4;
  int k = blockIdx.x * 16 + tx;
  int n = blockIdx.y * 16 + ty;
  if (k < K) Wt[(size_t)n * K + k] = f2bf(W[(size_t)k * 256 + n]);
}

// ---- MFMA GEMM + fused attention dots ----
#define BM 128
#define BN 128
#define BKG 64
#define LDK 72

__global__ __launch_bounds__(256) void gemm_bf16(const unsigned short* __restrict__ A,
    const unsigned short* __restrict__ Bt, unsigned short* __restrict__ Cbf,
    float* __restrict__ a_src, float* __restrict__ a_dst,
    const float* __restrict__ attS, const float* __restrict__ attD, int N, int K) {
  __shared__ unsigned short As[BM][LDK];
  __shared__ unsigned short Bs[BN][LDK];
  int t = threadIdx.x;
  int wave = t >> 6, lane = t & 63;
  int wm = wave & 1, wn = wave >> 1;
  int row0 = blockIdx.y * BM;
  int col0 = blockIdx.x * BN;
  floatx4 acc[4][4] = {};

  for (int k0 = 0; k0 < K; k0 += BKG) {
#pragma unroll
    for (int i = 0; i < 4; ++i) {
      int idx = t + 256 * i;
      int m = idx >> 3;
      int kk = (idx & 7) * 8;
      int r = row0 + m;
      uint4 v = make_uint4(0u, 0u, 0u, 0u);
      if (r < N) v = *(const uint4*)(A + (size_t)r * K + k0 + kk);
      *(uint4*)(&As[m][kk]) = v;
    }
#pragma unroll
    for (int i = 0; i < 4; ++i) {
      int idx = t + 256 * i;
      int n = idx >> 3;
      int kk = (idx & 7) * 8;
      uint4 v = *(const uint4*)(Bt + (size_t)(col0 + n) * K + k0 + kk);
      *(uint4*)(&Bs[n][kk]) = v;
    }
    __syncthreads();
    int mrow = lane & 15;
    int kq = (lane >> 4) * 8;
#pragma unroll
    for (int ks = 0; ks < BKG; ks += 32) {
      bf16x8 af[4], bfr[4];
#pragma unroll
      for (int i = 0; i < 4; ++i)
        af[i] = *(const bf16x8*)(&As[wm * 64 + i * 16 + mrow][kq + ks]);
#pragma unroll
      for (int j = 0; j < 4; ++j)
        bfr[j] = *(const bf16x8*)(&Bs[wn * 64 + j * 16 + mrow][kq + ks]);
#pragma unroll
      for (int i = 0; i < 4; ++i)
#pragma unroll
        for (int j = 0; j < 4; ++j)
          acc[i][j] = __builtin_amdgcn_mfma_f32_16x16x32_bf16(af[i], bfr[j], acc[i][j], 0, 0, 0);
    }
    __syncthreads();
  }

#pragma unroll
  for (int i = 0; i < 4; ++i) {
    int rb = row0 + wm * 64 + i * 16 + (lane >> 4) * 4;
#pragma unroll
    for (int j = 0; j < 4; ++j) {
      int c = col0 + wn * 64 + j * 16 + (lane & 15);
#pragma unroll
      for (int reg = 0; reg < 4; ++reg) {
        int r = rb + reg;
        if (r < N) Cbf[(size_t)r * 256 + c] = f2bf(acc[i][j][reg]);
      }
    }
  }

  int head = blockIdx.x * 2 + wn;
  int cin = lane & 15;
  float aS[4], aD[4];
#pragma unroll
  for (int j = 0; j < 4; ++j) {
    aS[j] = attS[head * 64 + j * 16 + cin];
    aD[j] = attD[head * 64 + j * 16 + cin];
  }
#pragma unroll
  for (int i = 0; i < 4; ++i) {
    floatx4 ps = {0.f, 0.f, 0.f, 0.f}, pd = {0.f, 0.f, 0.f, 0.f};
#pragma unroll
    for (int j = 0; j < 4; ++j) {
      ps += acc[i][j] * aS[j];
      pd += acc[i][j] * aD[j];
    }
#pragma unroll
    for (int m = 1; m < 16; m <<= 1) {
#pragma unroll
      for (int k = 0; k < 4; ++k) {
        ps[k] += __shfl_xor(ps[k], m, 64);
        pd[k] += __shfl_xor(pd[k], m, 64);
      }
    }
    if ((lane & 15) == 0) {
      int rb = row0 + wm * 64 + i * 16 + (lane >> 4) * 4;
#pragma unroll
      for (int reg = 0; reg < 4; ++reg) {
        int r = rb + reg;
        if (r < N) {
          a_src[r * 4 + head] = ps[reg];
          a_dst[r * 4 + head] = pd[reg];
        }
      }
    }
  }
}

// ---------------- per-edge exp(leaky(a_src[s]+a_dst[d])) for 4 heads ----------------
__global__ __launch_bounds__(256) void ealpha_k(const int* __restrict__ es,
    const int* __restrict__ ed, const float* __restrict__ a_src,
    const float* __restrict__ a_dst, float* __restrict__ ealpha, int Etot) {
  int e = blockIdx.x * 256 + threadIdx.x;
  if (e >= Etot) return;
  int s = es[e], d = ed[e];
  float4 as = *(const float4*)(a_src + (size_t)s * 4);
  float4 ad = *(const float4*)(a_dst + (size_t)d * 4);
  float4 r;
  r.x = expf(fminf(leaky(as.x + ad.x), 60.f));
  r.y = expf(fminf(leaky(as.y + ad.y), 60.f));
  r.z = expf(fminf(leaky(as.z + ad.z), 60.f));
  r.w = expf(fminf(leaky(as.w + ad.w), 60.f));
  *(float4*)(ealpha + (size_t)e * 4) = r;
}

// ---------------- per-dst softmax-normalize + aggregate + bias + tanh ----------------
// one wave per node. pass1: coalesced denom from ealpha. pass2: half-wave gather,
// 16B loads, 8 channels/lane, two edges in flight.
__global__ __launch_bounds__(256) void attn_agg(const unsigned short* __restrict__ g,
    const float* __restrict__ ealpha, const int* __restrict__ row_start,
    const int* __restrict__ edge_src, const float* __restrict__ bias,
    unsigned short* __restrict__ hout_bf, float* __restrict__ nodemean, int N) {
  int lane = threadIdx.x & 63;
  int n = blockIdx.x * 4 + (threadIdx.x >> 6);
  if (n >= N) return;
  int beg = row_start[n], end = row_start[n + 1];

  // pass 1: per-head denominators (coalesced float4 reads of ealpha)
  float4 dv = make_float4(0.f, 0.f, 0.f, 0.f);
  for (int i = beg + lane; i < end; i += 64) {
    float4 ev = *(const float4*)(ealpha + (size_t)i * 4);
    dv.x += ev.x; dv.y += ev.y; dv.z += ev.z; dv.w += ev.w;
  }
  for (int m = 1; m < 64; m <<= 1) {
    dv.x += __shfl_xor(dv.x, m, 64);
    dv.y += __shfl_xor(dv.y, m, 64);
    dv.z += __shfl_xor(dv.z, m, 64);
    dv.w += __shfl_xor(dv.w, m, 64);
  }

  int half = lane >> 5;
  int l = lane & 31;
  int h = l >> 3;          // head for this lane's 8 channels
  int c0 = l * 8;          // channel base (0..248)
  float den = (h == 0) ? dv.x : (h == 1) ? dv.y : (h == 2) ? dv.z : dv.w;
  float invh = 1.f / (den + SOFT_EPS);

  // pass 2: gather. half-wave processes alternating edges.
  float a0 = 0.f, a1 = 0.f, a2 = 0.f, a3 = 0.f, a4 = 0.f, a5 = 0.f, a6 = 0.f, a7 = 0.f;
  for (int i = beg + half; i < end; i += 2) {
    int s = edge_src[i];
    float al = ealpha[(size_t)i * 4 + h] * invh;
    uint4 gv = *(const uint4*)(g + (size_t)s * 256 + c0);
    a0 += al * bflo(gv.x); a1 += al * bfhi(gv.x);
    a2 += al * bflo(gv.y); a3 += al * bfhi(gv.y);
    a4 += al * bflo(gv.z); a5 += al * bfhi(gv.z);
    a6 += al * bflo(gv.w); a7 += al * bfhi(gv.w);
  }
  // combine the two halves (same channels, disjoint edge subsets)
  a0 += __shfl_xor(a0, 32, 64); a1 += __shfl_xor(a1, 32, 64);
  a2 += __shfl_xor(a2, 32, 64); a3 += __shfl_xor(a3, 32, 64);
  a4 += __shfl_xor(a4, 32, 64); a5 += __shfl_xor(a5, 32, 64);
  a6 += __shfl_xor(a6, 32, 64); a7 += __shfl_xor(a7, 32, 64);

  // bias + tanh (valid on lanes 0..31)
  float4 b01 = *(const float4*)(bias + c0);
  float4 b23 = *(const float4*)(bias + c0 + 4);
  float o0 = tanhf(a0 + b01.x), o1 = tanhf(a1 + b01.y);
  float o2 = tanhf(a2 + b01.z), o3 = tanhf(a3 + b01.w);
  float o4 = tanhf(a4 + b23.x), o5 = tanhf(a5 + b23.y);
  float o6 = tanhf(a6 + b23.z), o7 = tanhf(a7 + b23.w);

  if (hout_bf) {
    if (half == 0) {
      unsigned p0 = (unsigned)f2bf(o0) | ((unsigned)f2bf(o1) << 16);
      unsigned p1 = (unsigned)f2bf(o2) | ((unsigned)f2bf(o3) << 16);
      unsigned p2 = (unsigned)f2bf(o4) | ((unsigned)f2bf(o5) << 16);
      unsigned p3 = (unsigned)f2bf(o6) | ((unsigned)f2bf(o7) << 16);
      *(uint4*)(hout_bf + (size_t)n * 256 + c0) = make_uint4(p0, p1, p2, p3);
    }
  } else {
    // head-mean: channel j over heads = lanes l, l+8, l+16, l+24 (xor over bits 3,4)
    o0 += __shfl_xor(o0, 8, 64);  o1 += __shfl_xor(o1, 8, 64);
    o2 += __shfl_xor(o2, 8, 64);  o3 += __shfl_xor(o3, 8, 64);
    o4 += __shfl_xor(o4, 8, 64);  o5 += __shfl_xor(o5, 8, 64);
    o6 += __shfl_xor(o6, 8, 64);  o7 += __shfl_xor(o7, 8, 64);
    o0 += __shfl_xor(o0, 16, 64); o1 += __shfl_xor(o1, 16, 64);
    o2 += __shfl_xor(o2, 16, 64); o3 += __shfl_xor(o3, 16, 64);
    o4 += __shfl_xor(o4, 16, 64); o5 += __shfl_xor(o5, 16, 64);
    o6 += __shfl_xor(o6, 16, 64); o7 += __shfl_xor(o7, 16, 64);
    if (half == 0 && l < 8) {
      float* np = nodemean + (size_t)n * 64 + l * 8;
      *(float4*)(np)     = make_float4(0.25f * o0, 0.25f * o1, 0.25f * o2, 0.25f * o3);
      *(float4*)(np + 4) = make_float4(0.25f * o4, 0.25f * o5, 0.25f * o6, 0.25f * o7);
    }
  }
}

// ---------------- readout ----------------
__global__ void init_readout(unsigned* __restrict__ gmax, float* __restrict__ gsum,
                             int* __restrict__ cnt) {
  int t = threadIdx.x;
  for (int i = t; i < 64 * 64; i += 256) { gmax[i] = 0x007FFFFFu; gsum[i] = 0.f; }
  if (t < 64) cnt[t] = 0;
}

#define RNPB 256
__global__ __launch_bounds__(256) void readout_nodes(const float* __restrict__ nm,
    const int* __restrict__ batch, unsigned* __restrict__ gmax,
    float* __restrict__ gsum, int* __restrict__ cnt, int N) {
  int t = threadIdx.x;
  int c = t & 63;
  int q = t >> 6;
  int n0 = blockIdx.x * RNPB + q * (RNPB / 4);
  if (n0 >= N) return;
  int n1 = min(n0 + RNPB / 4, N);
  float vmax = -FLT_MAX, vsum = 0.f;
  int curb = batch[n0];
  int cl = 0;
  for (int n = n0; n < n1; ++n) {
    int b = batch[n];
    if (b != curb) {
      atomicMax(&gmax[curb * 64 + c], enc_f(vmax));
      atomicAdd(&gsum[curb * 64 + c], vsum);
      if (c == 0) atomicAdd(&cnt[curb], cl);
      vmax = -FLT_MAX; vsum = 0.f; cl = 0; curb = b;
    }
    float v = nm[(size_t)n * 64 + c];
    vmax = fmaxf(vmax, v); vsum += v; ++cl;
  }
  atomicMax(&gmax[curb * 64 + c], enc_f(vmax));
  atomicAdd(&gsum[curb * 64 + c], vsum);
  if (c == 0) atomicAdd(&cnt[curb], cl);
}

__global__ __launch_bounds__(256) void finalize(const unsigned* __restrict__ gmax,
    const float* __restrict__ gsum, const int* __restrict__ cnt,
    const float* __restrict__ Wout, const float* __restrict__ bout,
    float* __restrict__ out) {
  __shared__ float hid[64 * 192];
  int t = threadIdx.x;
  for (int i = t; i < 64 * 192; i += 256) {
    int b = i / 192, j = i % 192;
    float v;
    if (j < 64) v = dec_f(gmax[b * 64 + j]);
    else if (j < 128) v = gsum[b * 64 + j - 64] / fmaxf((float)cnt[b], 1.f);
    else v = gsum[b * 64 + j - 128];
    hid[i] = v;
    out[1024 + i] = v;
  }
  __syncthreads();
  for (int i = t; i < 64 * 16; i += 256) {
    int b = i >> 4, o = i & 15;
    float s = bout[o];
    for (int k = 0; k < 192; ++k) s += hid[b * 192 + k] * Wout[k * 16 + o];
    out[i] = s;
  }
}

extern "C" void kernel_launch(void* const* d_in, const int* in_sizes, int n_in,
                              void* d_out, int out_size, void* d_ws, size_t ws_size,
                              hipStream_t stream) {
  const float* x     = (const float*)d_in[0];
  const int*   ei    = (const int*)d_in[1];
  const int*   batch = (const int*)d_in[2];
  const float* W[3]  = {(const float*)d_in[3], (const float*)d_in[7], (const float*)d_in[11]};
  const float* as_[3] = {(const float*)d_in[4], (const float*)d_in[8], (const float*)d_in[12]};
  const float* ad_[3] = {(const float*)d_in[5], (const float*)d_in[9], (const float*)d_in[13]};
  const float* bb[3] = {(const float*)d_in[6], (const float*)d_in[10], (const float*)d_in[14]};
  const float* Wout  = (const float*)d_in[15];
  const float* bout  = (const float*)d_in[16];
  float* out = (float*)d_out;

  int N    = in_sizes[2];
  int Fin  = in_sizes[0] / N;
  int E    = in_sizes[1] / 2;
  int Etot = E + N;

  char* ws = (char*)d_ws;
  size_t off = 0;
  auto alloc = [&](size_t bytes) -> void* {
    void* p = ws + off;
    off += bytes;
    off = (off + 255) & ~(size_t)255;
    return p;
  };
  unsigned short* gbf  = (unsigned short*)alloc((size_t)N * 256 * 2);  // gemm out (bf16)
  unsigned short* h0bf = (unsigned short*)alloc((size_t)N * Fin * 2);  // x (bf16)
  unsigned short* h1bf = (unsigned short*)alloc((size_t)N * 256 * 2);  // layer out (bf16)
  float* nodemean  = (float*)alloc((size_t)N * 64 * 4);                // layer-2 head-mean
  float* ealpha    = (float*)alloc((size_t)Etot * 4 * 4);              // exp per edge-head
  unsigned short* Wt[3];
  Wt[0] = (unsigned short*)alloc((size_t)256 * Fin * 2);
  Wt[1] = (unsigned short*)alloc((size_t)256 * 256 * 2);
  Wt[2] = (unsigned short*)alloc((size_t)256 * 256 * 2);
  float* a_src    = (float*)alloc((size_t)N * 4 * 4);
  float* a_dst    = (float*)alloc((size_t)N * 4 * 4);
  int* counts     = (int*)alloc((size_t)N * 4);
  int* row_start  = (int*)alloc((size_t)(N + 1) * 4);
  int* write_ptr  = (int*)alloc((size_t)N * 4);
  int* edge_src   = (int*)alloc((size_t)Etot * 4);
  int* edge_dst   = (int*)alloc((size_t)Etot * 4);
  int* chunkSum   = (int*)alloc(64 * 4);
  int* chunkOff   = (int*)alloc(64 * 4);
  unsigned* gmax  = (unsigned*)alloc(64 * 64 * 4);
  float* gsum     = (float*)alloc(64 * 64 * 4);
  int* cnt        = (int*)alloc(64 * 4);

  // ---- CSR build ----
  hipMemsetAsync(counts, 0, (size_t)N * 4, stream);
  int nb = (N + 2047) / 2048;
  count_deg<<<(Etot + 255) / 256, 256, 0, stream>>>(ei, E, N, counts);
  chunk_sum<<<nb, 256, 0, stream>>>(counts, chunkSum, N);
  scan_chunks<<<1, 64, 0, stream>>>(chunkSum, chunkOff, nb, row_start, N, Etot);
  scan_emit<<<nb, 256, 0, stream>>>(counts, chunkOff, row_start, write_ptr, N);
  scatter_edges<<<(Etot + 255) / 256, 256, 0, stream>>>(ei, E, N, write_ptr, edge_src, edge_dst);

  // ---- weight transpose-convert, x convert ----
  cvt_wt<<<dim3((Fin + 15) / 16, 16), 256, 0, stream>>>(W[0], Wt[0], Fin);
  cvt_wt<<<dim3(16, 16), 256, 0, stream>>>(W[1], Wt[1], 256);
  cvt_wt<<<dim3(16, 16), 256, 0, stream>>>(W[2], Wt[2], 256);
  cvt_bf16<<<((N * Fin / 4) + 255) / 256, 256, 0, stream>>>(x, h0bf, N * Fin / 4);

  // ---- 3 GAT layers ----
  const unsigned short* Ain = h0bf;
  int K = Fin;
  for (int l = 0; l < 3; ++l) {
    dim3 gg(2, (N + BM - 1) / BM);
    gemm_bf16<<<gg, 256, 0, stream>>>(Ain, Wt[l], gbf, a_src, a_dst, as_[l], ad_[l], N, K);
    ealpha_k<<<(Etot + 255) / 256, 256, 0, stream>>>(edge_src, edge_dst, a_src, a_dst,
                                                     ealpha, Etot);
    attn_agg<<<(N + 3) / 4, 256, 0, stream>>>(gbf, ealpha, row_start, edge_src, bb[l],
                                              (l < 2) ? h1bf : (unsigned short*)nullptr,
                                              (l == 2) ? nodemean : (float*)nullptr, N);
    Ain = h1bf;
    K = 256;
  }

  // ---- readout ----
  init_readout<<<1, 256, 0, stream>>>(gmax, gsum, cnt);
  readout_nodes<<<(N + RNPB - 1) / RNPB, 256, 0, stream>>>(nodemean, batch, gmax, gsum, cnt, N);
  finalize<<<1, 256, 0, stream>>>(gmax, gsum, cnt, Wout, bout, out);
}